// Round 7
// baseline (551.094 us; speedup 1.0000x reference)
//
#include <hip/hip_runtime.h>
#include <hip/hip_bf16.h>
#include <hip/hip_cooperative_groups.h>

namespace cg = cooperative_groups;

#define NN 50000
#define EE 400000
#define EP 450000        // EE + NN self-loops
#define BPG 640
#define TPB 256
#define NTH (BPG * TPB)  // 163840 threads
#define NWV (NTH / 64)   // 2560 waves
#define CHUNK 79         // ceil(NN/BPG): nodes per block in the scan

typedef __attribute__((ext_vector_type(8))) short short8;
typedef __attribute__((ext_vector_type(4))) float f32x4;

__device__ __forceinline__ float bf2f(__hip_bfloat16 b) { return __bfloat162float(b); }
__device__ __forceinline__ float us2f(unsigned short u) {
    unsigned int x = ((unsigned int)u) << 16;
    union { unsigned int i; float f; } c; c.i = x; return c.f;
}
__device__ __forceinline__ unsigned short f2bfu(float f) {   // f32 -> bf16 bits, RNE
    union { float f; unsigned int u; } c; c.f = f;
    unsigned int r = c.u + 0x7FFFu + ((c.u >> 16) & 1u);
    return (unsigned short)(r >> 16);
}

__device__ __forceinline__ short8 load_frag(const __hip_bfloat16* p) {
    return *(const short8*)p;
}
__device__ __forceinline__ short8 load_frag(const float* p) {
    const float4* q = (const float4*)p;
    float4 a = q[0], b = q[1];
    short8 r;
    r[0] = (short)f2bfu(a.x); r[1] = (short)f2bfu(a.y);
    r[2] = (short)f2bfu(a.z); r[3] = (short)f2bfu(a.w);
    r[4] = (short)f2bfu(b.x); r[5] = (short)f2bfu(b.y);
    r[6] = (short)f2bfu(b.z); r[7] = (short)f2bfu(b.w);
    return r;
}

struct Params {
    const float* x; const int* ei;
    const float *ea, *yr, *qt;
    const float *W1, *a1s, *a1d, *b1;
    const float *W2, *a2s, *a2d, *b2;
    const float *W3, *a3s, *a3d, *b3;
    const float *fc1w, *fc1b, *fc2w, *fc2b;
    float* outp;
    __hip_bfloat16 *h, *act, *h3, *act3;
    float *s, *d, *s3, *d3;
    int *deg, *cursor, *offsets, *elist, *blocksum;
    __hip_bfloat16 *w1b, *w2b;
};

// A-stationary GEMM + fused s/d epilogue. 50000 = 3125*16 exactly -> no guards.
template<int K, int H, int C, typename TA>
__device__ void gemm_phase(const TA* __restrict__ A, const __hip_bfloat16* __restrict__ Wb,
                           const float* __restrict__ as_, const float* __restrict__ ad_,
                           __hip_bfloat16* __restrict__ Cb,
                           float* __restrict__ s, float* __restrict__ d, int wid) {
    constexpr int NO = H * C, NK = K / 32;
    int lane = threadIdx.x & 63;
    int r = lane & 15, quad = lane >> 4;
    for (int g = wid; g < NN / 16; g += NWV) {
        int m0 = g * 16;
        short8 afrag[NK];
        const TA* arow = A + (size_t)(m0 + r) * K + quad * 8;
#pragma unroll
        for (int kk = 0; kk < NK; kk++) afrag[kk] = load_frag(arow + kk * 32);
        const __hip_bfloat16* wrow = Wb + (size_t)r * K + quad * 8;
        float sacc[4] = {0.f, 0.f, 0.f, 0.f};
        float dacc[4] = {0.f, 0.f, 0.f, 0.f};
        for (int n0 = 0; n0 < NO; n0 += 16) {
            f32x4 acc = {0.f, 0.f, 0.f, 0.f};
#pragma unroll
            for (int kk = 0; kk < NK; kk++) {
                short8 b = *(const short8*)(wrow + (size_t)n0 * K + kk * 32);
                acc = __builtin_amdgcn_mfma_f32_16x16x32_bf16(afrag[kk], b, acc, 0, 0, 0);
            }
            float as_v = as_[n0 + r], ad_v = ad_[n0 + r];
#pragma unroll
            for (int i = 0; i < 4; i++) {
                Cb[(size_t)(m0 + quad * 4 + i) * NO + n0 + r] = __float2bfloat16(acc[i]);
                sacc[i] += acc[i] * as_v;
                dacc[i] += acc[i] * ad_v;
            }
            if ((n0 & (C - 16)) == C - 16) {   // head boundary: reduce over 16 r-lanes
                int hh = n0 / C;
#pragma unroll
                for (int mask = 1; mask <= 8; mask <<= 1)
#pragma unroll
                    for (int i = 0; i < 4; i++) {
                        sacc[i] += __shfl_xor(sacc[i], mask, 64);
                        dacc[i] += __shfl_xor(dacc[i], mask, 64);
                    }
                if (r == 0)
#pragma unroll
                    for (int i = 0; i < 4; i++) {
                        int m = m0 + quad * 4 + i;
                        s[m * H + hh] = sacc[i]; d[m * H + hh] = dacc[i];
                    }
#pragma unroll
                for (int i = 0; i < 4; i++) { sacc[i] = 0.f; dacc[i] = 0.f; }
            }
        }
    }
}

__global__ __launch_bounds__(TPB, 3) void mega(Params p) {
    cg::grid_group grid = cg::this_grid();
    int tid = threadIdx.x;
    int gtid = blockIdx.x * TPB + tid;
    int wid = gtid >> 6;
    int lane = tid & 63;

    __shared__ float smf[352];   // p9: fc1w 304 + fc1b 16 + fc2w 16
    __shared__ int smi[256];     // p2 scans

    // ---- p0: zero deg+cursor (contiguous) + weight cvt ----
    for (int i = gtid; i < 2 * NN; i += NTH) p.deg[i] = 0;
    for (int i = gtid; i < 65536; i += NTH) p.w1b[i] = __float2bfloat16(p.W1[i]);
    for (int i = gtid; i < 65536; i += NTH) p.w2b[i] = __float2bfloat16(p.W2[i]);
    grid.sync();

    // ---- p1: degree histogram ----
    for (int e = gtid; e < EP; e += NTH) {
        int dst = (e < EE) ? p.ei[EE + e] : e - EE;
        atomicAdd(&p.deg[dst], 1);
    }
    grid.sync();

    // ---- p2a: per-block chunk sums ----
    {
        int lo = blockIdx.x * CHUNK;
        int v = (tid < CHUNK && lo + tid < NN) ? p.deg[lo + tid] : 0;
        smi[tid] = v; __syncthreads();
        for (int off = 128; off > 0; off >>= 1) {
            if (tid < off) smi[tid] += smi[tid + off];
            __syncthreads();
        }
        if (tid == 0) p.blocksum[blockIdx.x] = smi[0];
    }
    grid.sync();

    // ---- p2b: block 0 exclusive-scans the BPG block sums (3 per thread) ----
    if (blockIdx.x == 0) {
        int i0 = 3 * tid, i1 = 3 * tid + 1, i2 = 3 * tid + 2;
        int b0 = (i0 < BPG) ? p.blocksum[i0] : 0;
        int b1v = (i1 < BPG) ? p.blocksum[i1] : 0;
        int b2v = (i2 < BPG) ? p.blocksum[i2] : 0;
        int trio = b0 + b1v + b2v;
        smi[tid] = trio; __syncthreads();
        for (int off = 1; off < 256; off <<= 1) {
            int u = (tid >= off) ? smi[tid - off] : 0;
            __syncthreads();
            smi[tid] += u;
            __syncthreads();
        }
        int excl = smi[tid] - trio;
        if (i0 < BPG) p.blocksum[i0] = excl;
        if (i1 < BPG) p.blocksum[i1] = excl + b0;
        if (i2 < BPG) p.blocksum[i2] = excl + b0 + b1v;
    }
    grid.sync();

    // ---- p2c: per-block local exclusive scan -> offsets ----
    {
        int lo = blockIdx.x * CHUNK;
        int dv = (tid < CHUNK && lo + tid < NN) ? p.deg[lo + tid] : 0;
        smi[tid] = dv; __syncthreads();
        for (int off = 1; off < 256; off <<= 1) {
            int u = (tid >= off) ? smi[tid - off] : 0;
            __syncthreads();
            smi[tid] += u;
            __syncthreads();
        }
        if (tid < CHUNK && lo + tid < NN)
            p.offsets[lo + tid] = p.blocksum[blockIdx.x] + smi[tid] - dv;
        if (gtid == 0) p.offsets[NN] = EP;
    }
    grid.sync();

    // ---- p3: fill dst-sorted src list ----
    for (int e = gtid; e < EP; e += NTH) {
        int src, dst;
        if (e < EE) { src = p.ei[e]; dst = p.ei[EE + e]; } else { src = dst = e - EE; }
        int pos = atomicAdd(&p.cursor[dst], 1);
        p.elist[p.offsets[dst] + pos] = src;
    }
    grid.sync();

    // ---- p4: layer-1 GEMM (128 -> 4x128) + s/d ----
    gemm_phase<128, 4, 128, float>(p.x, p.w1b, p.a1s, p.a1d, p.h, p.s, p.d, wid);
    grid.sync();

    // ---- p5: layer-1 gather (64 thr/node, 8 ch/thr) ----
    for (int i = gtid; i < NN * 64; i += NTH) {
        int node = i >> 6, t = i & 63;
        int c0 = t * 8, hh = t >> 4;
        int j0 = p.offsets[node], j1 = p.offsets[node + 1];
        float dv = p.d[node * 4 + hh];
        float den = 0.f, acc[8] = {0,0,0,0,0,0,0,0};
        const unsigned short* hb = (const unsigned short*)p.h;
        for (int j = j0; j < j1; j++) {
            int src = p.elist[j];
            float xx = p.s[src * 4 + hh] + dv;
            xx = xx > 0.f ? xx : 0.2f * xx;
            float w = __expf(xx);
            den += w;
            const unsigned short* hp = hb + (size_t)src * 512 + c0;
            ushort4 a = *(const ushort4*)hp;
            ushort4 b = *(const ushort4*)(hp + 4);
            acc[0] += w * us2f(a.x); acc[1] += w * us2f(a.y);
            acc[2] += w * us2f(a.z); acc[3] += w * us2f(a.w);
            acc[4] += w * us2f(b.x); acc[5] += w * us2f(b.y);
            acc[6] += w * us2f(b.z); acc[7] += w * us2f(b.w);
        }
        float inv = 1.0f / den;
        __hip_bfloat16* op = p.act + (size_t)node * 512 + c0;
#pragma unroll
        for (int c = 0; c < 8; c++) {
            float v = acc[c] * inv + p.b1[c0 + c];
            v = v > 0.f ? v : (__expf(v) - 1.0f);
            op[c] = __float2bfloat16(v);
        }
    }
    grid.sync();

    // ---- p6: layer-2 GEMM (512 -> 4x32) + s/d ----
    gemm_phase<512, 4, 32, __hip_bfloat16>(p.act, p.w2b, p.a2s, p.a2d, p.h, p.s, p.d, wid);
    grid.sync();

    // ---- p7: layer-2 gather (1 wave/node, 2 ch/lane) + fused gemm8 + s3/d3 ----
    {
        int c0 = 2 * lane, hh = lane >> 4;
        float w3a[8], w3b[8], as3[8], ad3[8];
#pragma unroll
        for (int c = 0; c < 8; c++) {
            w3a[c] = p.W3[c * 128 + c0]; w3b[c] = p.W3[c * 128 + c0 + 1];
            as3[c] = p.a3s[c]; ad3[c] = p.a3d[c];
        }
        float bb0 = p.b2[c0], bb1 = p.b2[c0 + 1];
        const unsigned short* hb = (const unsigned short*)p.h;
        for (int node = wid; node < NN; node += NWV) {
            int j0 = p.offsets[node], j1 = p.offsets[node + 1];
            float dv = p.d[node * 4 + hh];
            float den = 0.f, a0 = 0.f, a1 = 0.f;
            for (int j = j0; j < j1; j++) {
                int src = p.elist[j];
                float xx = p.s[src * 4 + hh] + dv;
                xx = xx > 0.f ? xx : 0.2f * xx;
                float w = __expf(xx);
                den += w;
                ushort2 hv = *(const ushort2*)(hb + (size_t)src * 128 + c0);
                a0 += w * us2f(hv.x);
                a1 += w * us2f(hv.y);
            }
            float inv = 1.0f / den;
            a0 = a0 * inv + bb0; a0 = a0 > 0.f ? a0 : (__expf(a0) - 1.0f);
            a1 = a1 * inv + bb1; a1 = a1 > 0.f ? a1 : (__expf(a1) - 1.0f);
            float pc[8], s3p = 0.f, d3p = 0.f;
#pragma unroll
            for (int c = 0; c < 8; c++) {
                pc[c] = a0 * w3a[c] + a1 * w3b[c];
                s3p += pc[c] * as3[c];
                d3p += pc[c] * ad3[c];
            }
#pragma unroll
            for (int mask = 1; mask <= 32; mask <<= 1) {
#pragma unroll
                for (int c = 0; c < 8; c++) pc[c] += __shfl_xor(pc[c], mask, 64);
                s3p += __shfl_xor(s3p, mask, 64);
                d3p += __shfl_xor(d3p, mask, 64);
            }
            if (lane == 0) {
#pragma unroll
                for (int c = 0; c < 8; c++) p.h3[node * 8 + c] = __float2bfloat16(pc[c]);
                p.s3[node] = s3p;
                p.d3[node] = d3p;
            }
        }
    }
    grid.sync();

    // ---- p8: layer-3 gather (1 thr/node) ----
    {
        const unsigned short* h3b = (const unsigned short*)p.h3;
        for (int node = gtid; node < NN; node += NTH) {
            int j0 = p.offsets[node], j1 = p.offsets[node + 1];
            float dv = p.d3[node];
            float den = 0.f, acc[8] = {0,0,0,0,0,0,0,0};
            for (int j = j0; j < j1; j++) {
                int src = p.elist[j];
                float xx = p.s3[src] + dv;
                xx = xx > 0.f ? xx : 0.2f * xx;
                float w = __expf(xx);
                den += w;
                ushort4 q0 = *(const ushort4*)(h3b + src * 8);
                ushort4 q1 = *(const ushort4*)(h3b + src * 8 + 4);
                acc[0] += w * us2f(q0.x); acc[1] += w * us2f(q0.y);
                acc[2] += w * us2f(q0.z); acc[3] += w * us2f(q0.w);
                acc[4] += w * us2f(q1.x); acc[5] += w * us2f(q1.y);
                acc[6] += w * us2f(q1.z); acc[7] += w * us2f(q1.w);
            }
            float inv = 1.0f / den;
#pragma unroll
            for (int c = 0; c < 8; c++) {
                float v = acc[c] * inv + p.b3[c];
                v = v > 0.f ? v : (__expf(v) - 1.0f);
                p.act3[node * 8 + c] = __float2bfloat16(v);
            }
        }
    }
    grid.sync();

    // ---- p9: final edge MLP ----
    {
        float* w1 = smf;
        float* b1s = smf + 304;
        float* w2 = smf + 320;
        for (int i = tid; i < 304; i += TPB) w1[i] = p.fc1w[i];
        if (tid < 16) { b1s[tid] = p.fc1b[tid]; w2[tid] = p.fc2w[tid]; }
        __syncthreads();
        float f2b = p.fc2b[0];
        for (int e = gtid; e < EE; e += NTH) {
            int src = p.ei[e], dst = p.ei[EE + e];
            float z[19];
#pragma unroll
            for (int i = 0; i < 8; i++) z[i] = bf2f(p.act3[src * 8 + i]);
#pragma unroll
            for (int i = 0; i < 8; i++) z[8 + i] = bf2f(p.act3[dst * 8 + i]);
            z[16] = p.ea[e]; z[17] = p.yr[e]; z[18] = p.qt[e];
            float acc2 = f2b;
#pragma unroll
            for (int j = 0; j < 16; j++) {
                float a = b1s[j];
#pragma unroll
                for (int i = 0; i < 19; i++) a += z[i] * w1[j * 19 + i];
                a = a > 0.f ? a : 0.f;
                acc2 += a * w2[j];
            }
            p.outp[e] = acc2;
        }
    }
}

// ===========================================================================
// Fallback multi-kernel pipeline (R5, known-good) — used if cooperative
// launch is not possible (occupancy gate) or is rejected at call time.
// ===========================================================================
__global__ void cvt2_kernel(const float* __restrict__ W1, const float* __restrict__ W2,
                            __hip_bfloat16* __restrict__ w1b, __hip_bfloat16* __restrict__ w2b) {
    int i = blockIdx.x * blockDim.x + threadIdx.x;
    if (i < 65536) w1b[i] = __float2bfloat16(W1[i]);
    else if (i < 131072) w2b[i - 65536] = __float2bfloat16(W2[i - 65536]);
}

template<int K, int H, int C, typename TA>
__global__ void gemm_rows(const TA* __restrict__ A,
                          const __hip_bfloat16* __restrict__ Wb,
                          const float* __restrict__ as_, const float* __restrict__ ad_,
                          __hip_bfloat16* __restrict__ Cb,
                          float* __restrict__ s, float* __restrict__ d,
                          int M) {
    constexpr int NO = H * C;
    int wave = threadIdx.x >> 6;
    int lane = threadIdx.x & 63;
    int m0 = blockIdx.x * 64 + wave * 16;
    int r = lane & 15, quad = lane >> 4;
    int am = m0 + r; if (am >= M) am = M - 1;
    constexpr int NK = K / 32;
    short8 afrag[NK];
    const TA* arow = A + (size_t)am * K + quad * 8;
#pragma unroll
    for (int kk = 0; kk < NK; kk++) afrag[kk] = load_frag(arow + kk * 32);
    const __hip_bfloat16* wrow = Wb + (size_t)r * K + quad * 8;
    float sacc[4] = {0.f, 0.f, 0.f, 0.f};
    float dacc[4] = {0.f, 0.f, 0.f, 0.f};
    for (int n0 = 0; n0 < NO; n0 += 16) {
        f32x4 acc = {0.f, 0.f, 0.f, 0.f};
#pragma unroll
        for (int kk = 0; kk < NK; kk++) {
            short8 b = *(const short8*)(wrow + (size_t)n0 * K + kk * 32);
            acc = __builtin_amdgcn_mfma_f32_16x16x32_bf16(afrag[kk], b, acc, 0, 0, 0);
        }
        float as_v = as_[n0 + r];
        float ad_v = ad_[n0 + r];
#pragma unroll
        for (int i = 0; i < 4; i++) {
            int m = m0 + quad * 4 + i;
            if (m < M) Cb[(size_t)m * NO + n0 + r] = __float2bfloat16(acc[i]);
            sacc[i] += acc[i] * as_v;
            dacc[i] += acc[i] * ad_v;
        }
        if ((n0 & (C - 16)) == C - 16) {
            int hh = n0 / C;
#pragma unroll
            for (int mask = 1; mask <= 8; mask <<= 1)
#pragma unroll
                for (int i = 0; i < 4; i++) {
                    sacc[i] += __shfl_xor(sacc[i], mask, 64);
                    dacc[i] += __shfl_xor(dacc[i], mask, 64);
                }
            if (r == 0)
#pragma unroll
                for (int i = 0; i < 4; i++) {
                    int m = m0 + quad * 4 + i;
                    if (m < M) { s[m * H + hh] = sacc[i]; d[m * H + hh] = dacc[i]; }
                }
#pragma unroll
            for (int i = 0; i < 4; i++) { sacc[i] = 0.f; dacc[i] = 0.f; }
        }
    }
}

__global__ void gemm8_kernel(const __hip_bfloat16* __restrict__ A,
                             const float* __restrict__ W,
                             const float* __restrict__ a3s, const float* __restrict__ a3d,
                             __hip_bfloat16* __restrict__ Cb,
                             float* __restrict__ s, float* __restrict__ d) {
    int gid = blockIdx.x * blockDim.x + threadIdx.x;
    if (gid >= NN * 8) return;
    int n = gid >> 3, c = gid & 7;
    const __hip_bfloat16* ap = A + (size_t)n * 128;
    const float* wp = W + c * 128;
    float acc = 0.f;
#pragma unroll 8
    for (int k = 0; k < 128; k++) acc += bf2f(ap[k]) * wp[k];
    Cb[gid] = __float2bfloat16(acc);
    float sv = acc * a3s[c];
    float dv = acc * a3d[c];
#pragma unroll
    for (int mask = 1; mask <= 4; mask <<= 1) {
        sv += __shfl_xor(sv, mask, 64);
        dv += __shfl_xor(dv, mask, 64);
    }
    if (c == 0) { s[n] = sv; d[n] = dv; }
}

__global__ void deg_kernel(const int* __restrict__ ei, int* __restrict__ deg) {
    int e = blockIdx.x * blockDim.x + threadIdx.x;
    if (e >= EP) return;
    int dst = (e < EE) ? ei[EE + e] : e - EE;
    atomicAdd(&deg[dst], 1);
}

#define SCAN_T 1024
__global__ void scan_kernel(const int* __restrict__ deg, int* __restrict__ offsets) {
    __shared__ int part[SCAN_T];
    int t = threadIdx.x;
    constexpr int CH = (NN + SCAN_T - 1) / SCAN_T;
    int lo = t * CH;
    int hi = lo + CH; if (hi > NN) hi = NN;
    int s = 0;
    for (int i = lo; i < hi && i < NN; i++) s += deg[i];
    part[t] = s;
    __syncthreads();
    for (int off = 1; off < SCAN_T; off <<= 1) {
        int v = (t >= off) ? part[t - off] : 0;
        __syncthreads();
        part[t] += v;
        __syncthreads();
    }
    int run = (t == 0) ? 0 : part[t - 1];
    for (int i = lo; i < hi && i < NN; i++) { offsets[i] = run; run += deg[i]; }
    if (t == SCAN_T - 1) offsets[NN] = run;
}

__global__ void fill_kernel(const int* __restrict__ ei, const int* __restrict__ offsets,
                            int* __restrict__ cursor, int* __restrict__ elist) {
    int e = blockIdx.x * blockDim.x + threadIdx.x;
    if (e >= EP) return;
    int src, dst;
    if (e < EE) { src = ei[e]; dst = ei[EE + e]; } else { src = dst = e - EE; }
    int pos = atomicAdd(&cursor[dst], 1);
    elist[offsets[dst] + pos] = src;
}

template<int H, int C, int CPL>
__global__ void gather_fused(const int* __restrict__ elist,
                             const int* __restrict__ offsets,
                             const __hip_bfloat16* __restrict__ h,
                             const float* __restrict__ s, const float* __restrict__ d,
                             const float* __restrict__ b,
                             __hip_bfloat16* __restrict__ act) {
    constexpr int HC = H * C;
    constexpr int TPN = HC / CPL;
    int gid = blockIdx.x * blockDim.x + threadIdx.x;
    if (gid >= NN * TPN) return;
    int node = gid / TPN;
    int t = gid - node * TPN;
    int c0 = t * CPL;
    int hh = c0 / C;
    int j0 = offsets[node], j1 = offsets[node + 1];
    float dv = d[node * H + hh];
    float den = 0.f;
    float acc[CPL];
#pragma unroll
    for (int c = 0; c < CPL; c++) acc[c] = 0.f;
    const unsigned short* hb = (const unsigned short*)h;
    for (int j = j0; j < j1; j++) {
        int src = elist[j];
        float x = s[src * H + hh] + dv;
        x = x > 0.f ? x : 0.2f * x;
        float w = __expf(x);
        den += w;
        const unsigned short* hp = hb + (size_t)src * HC + c0;
        if constexpr (CPL == 8) {
            ushort4 a = *(const ushort4*)hp;
            ushort4 bb = *(const ushort4*)(hp + 4);
            acc[0] += w * us2f(a.x);  acc[1] += w * us2f(a.y);
            acc[2] += w * us2f(a.z);  acc[3] += w * us2f(a.w);
            acc[4] += w * us2f(bb.x); acc[5] += w * us2f(bb.y);
            acc[6] += w * us2f(bb.z); acc[7] += w * us2f(bb.w);
        } else {
            ushort2 a = *(const ushort2*)hp;
            acc[0] += w * us2f(a.x);
            acc[1] += w * us2f(a.y);
        }
    }
    float inv = 1.0f / den;
    __hip_bfloat16* op = act + (size_t)node * HC + c0;
#pragma unroll
    for (int c = 0; c < CPL; c++) {
        float v = acc[c] * inv + b[c0 + c];
        v = v > 0.f ? v : (__expf(v) - 1.0f);
        op[c] = __float2bfloat16(v);
    }
}

__global__ void mlp_kernel(const int* __restrict__ ei,
                           const __hip_bfloat16* __restrict__ act3,
                           const float* __restrict__ ea,
                           const float* __restrict__ yr,
                           const float* __restrict__ qt,
                           const float* __restrict__ fc1w,
                           const float* __restrict__ fc1b,
                           const float* __restrict__ fc2w,
                           const float* __restrict__ fc2b,
                           float* __restrict__ outp) {
    __shared__ float w1[16 * 19], b1s[16], w2[16];
    for (int i = threadIdx.x; i < 16 * 19; i += blockDim.x) w1[i] = fc1w[i];
    if (threadIdx.x < 16) {
        b1s[threadIdx.x] = fc1b[threadIdx.x];
        w2[threadIdx.x] = fc2w[threadIdx.x];
    }
    __syncthreads();
    int e = blockIdx.x * blockDim.x + threadIdx.x;
    if (e >= EE) return;
    int src = ei[e], dst = ei[EE + e];
    float z[19];
#pragma unroll
    for (int i = 0; i < 8; i++) z[i] = bf2f(act3[src * 8 + i]);
#pragma unroll
    for (int i = 0; i < 8; i++) z[8 + i] = bf2f(act3[dst * 8 + i]);
    z[16] = ea[e]; z[17] = yr[e]; z[18] = qt[e];
    float acc2 = fc2b[0];
#pragma unroll
    for (int j = 0; j < 16; j++) {
        float a = b1s[j];
#pragma unroll
        for (int i = 0; i < 19; i++) a += z[i] * w1[j * 19 + i];
        a = a > 0.f ? a : 0.f;
        acc2 += a * w2[j];
    }
    outp[e] = acc2;
}

// ---------------------------------------------------------------------------
extern "C" void kernel_launch(void* const* d_in, const int* in_sizes, int n_in,
                              void* d_out, int out_size, void* d_ws, size_t ws_size,
                              hipStream_t stream) {
    Params p;
    p.x    = (const float*)d_in[0];
    p.ei   = (const int*)d_in[1];
    p.ea   = (const float*)d_in[2];
    p.yr   = (const float*)d_in[3];
    p.qt   = (const float*)d_in[4];
    p.W1   = (const float*)d_in[5];
    p.a1s  = (const float*)d_in[6];
    p.a1d  = (const float*)d_in[7];
    p.b1   = (const float*)d_in[8];
    p.W2   = (const float*)d_in[9];
    p.a2s  = (const float*)d_in[10];
    p.a2d  = (const float*)d_in[11];
    p.b2   = (const float*)d_in[12];
    p.W3   = (const float*)d_in[13];
    p.a3s  = (const float*)d_in[14];
    p.a3d  = (const float*)d_in[15];
    p.b3   = (const float*)d_in[16];
    p.fc1w = (const float*)d_in[17];
    p.fc1b = (const float*)d_in[18];
    p.fc2w = (const float*)d_in[19];
    p.fc2b = (const float*)d_in[20];
    p.outp = (float*)d_out;

    char* ws = (char*)d_ws;
    p.h        = (__hip_bfloat16*)(ws);                    // N*512 bf16 (51.2 MB)
    p.act      = (__hip_bfloat16*)(ws + 51200000);         // N*512 bf16 (51.2 MB)
    p.s        = (float*)(ws + 102400000);                 // N*4
    p.d        = (float*)(ws + 103200000);                 // N*4
    p.s3       = (float*)(ws + 104000000);                 // N
    p.d3       = (float*)(ws + 104200000);                 // N
    p.deg      = (int*)  (ws + 104400000);                 // N
    p.cursor   = (int*)  (ws + 104600000);                 // N (contiguous with deg)
    p.offsets  = (int*)  (ws + 104800000);                 // N+1
    p.elist    = (int*)  (ws + 105000016);                 // EP (1.8 MB)
    p.blocksum = (int*)  (ws + 106800016);                 // BPG
    p.w1b      = (__hip_bfloat16*)(ws + 106803104);        // 512*128
    p.w2b      = (__hip_bfloat16*)(ws + 106934176);        // 128*512
    p.h3       = (__hip_bfloat16*)(ws + 107065248);        // N*8
    p.act3     = (__hip_bfloat16*)(ws + 107865248);        // N*8

    // Occupancy gate: only use cooperative launch if BPG blocks can be
    // co-resident. Pure host-side computation -> graph-capture-safe and
    // deterministic across calls.
    int nb = 0;
    hipError_t oe = hipOccupancyMaxActiveBlocksPerMultiprocessor(&nb, mega, TPB, 0);
    if (oe == hipSuccess && nb * 256 >= BPG) {
        void* kargs[] = { (void*)&p };
        hipError_t le = hipLaunchCooperativeKernel((const void*)mega, dim3(BPG), dim3(TPB),
                                                   kargs, 0, stream);
        if (le == hipSuccess) return;
    }

    // ---- Fallback: R5 multi-kernel pipeline ----
    hipMemsetAsync(p.deg, 0, 2 * NN * sizeof(int), stream);          // deg + cursor
    deg_kernel<<<(EP + 255) / 256, 256, 0, stream>>>(p.ei, p.deg);
    cvt2_kernel<<<(131072 + 255) / 256, 256, 0, stream>>>(p.W1, p.W2, p.w1b, p.w2b);
    scan_kernel<<<1, SCAN_T, 0, stream>>>(p.deg, p.offsets);
    fill_kernel<<<(EP + 255) / 256, 256, 0, stream>>>(p.ei, p.offsets, p.cursor, p.elist);

    gemm_rows<128, 4, 128, float><<<(NN + 63) / 64, 256, 0, stream>>>(
        p.x, p.w1b, p.a1s, p.a1d, p.h, p.s, p.d, NN);
    gather_fused<4, 128, 8><<<(NN * 64 + 255) / 256, 256, 0, stream>>>(
        p.elist, p.offsets, p.h, p.s, p.d, p.b1, p.act);

    gemm_rows<512, 4, 32, __hip_bfloat16><<<(NN + 63) / 64, 256, 0, stream>>>(
        p.act, p.w2b, p.a2s, p.a2d, p.h, p.s, p.d, NN);
    gather_fused<4, 32, 2><<<(NN * 64 + 255) / 256, 256, 0, stream>>>(
        p.elist, p.offsets, p.h, p.s, p.d, p.b2, p.act);

    gemm8_kernel<<<(NN * 8 + 255) / 256, 256, 0, stream>>>(
        p.act, p.W3, p.a3s, p.a3d, p.h, p.s, p.d);
    gather_fused<1, 8, 8><<<(NN + 255) / 256, 256, 0, stream>>>(
        p.elist, p.offsets, p.h, p.s, p.d, p.b3, p.act);

    mlp_kernel<<<(EE + 255) / 256, 256, 0, stream>>>(p.ei, p.act, p.ea, p.yr, p.qt,
                                                     p.fc1w, p.fc1b, p.fc2w, p.fc2b, p.outp);
}